// Round 2
// baseline (651.899 us; speedup 1.0000x reference)
//
#include <hip/hip_runtime.h>
#include <hip/hip_cooperative_groups.h>
#include <math.h>

namespace cg = cooperative_groups;

#define HSZ 8192
#define ISZ 4096
#define OSZ 4096
#define NTOT (HSZ + OSZ)
#define STEPS 100

typedef unsigned short ushort8v __attribute__((ext_vector_type(8)));

__device__ __forceinline__ float bf2f(unsigned short h) {
    union { unsigned u; float f; } c; c.u = ((unsigned)h) << 16; return c.f;
}

__device__ __forceinline__ double compress_d(double x, double gain) {
    // sign(x) * log1p(gain*|x| + 1e-6), sign(0)==0
    double s = (x > 0.0) ? 1.0 : ((x < 0.0) ? -1.0 : 0.0);
    return s * log1p(gain * fabs(x) + 1e-6);
}

__device__ __forceinline__ double wred(double a) {
    #pragma unroll
    for (int o = 32; o > 0; o >>= 1) a += __shfl_down(a, o, 64);
    return a;
}

// bf16-vs-fp32 detection, uniform per wave. W1 ~ U(0,0.05): true bf16 -> all
// |values| <= 0.05; fp32 bits read as ushorts -> random exponents, some
// |bf16(bits)| > 0.0625 (0x3D80) almost surely.
__device__ __forceinline__ int detect_bf(const void* W1) {
    const unsigned short* p = (const unsigned short*)W1;
    const int lane = threadIdx.x & 63;
    const unsigned short a0 = (unsigned short)(p[lane] & 0x7FFF);
    const unsigned short a1 = (unsigned short)(p[64 + lane] & 0x7FFF);
    unsigned long long bad = __ballot((a0 > 0x3D80) || (a1 > 0x3D80));
    return bad == 0ull;
}

// Exact f64 dot of W[row,:] with x, computed by ONE wave (64 lanes), lane-
// interleaved 16B loads (deep independent load queue), shfl-only reduction
// (no __syncthreads -> safe inside divergent grid-stride loops).
// XIN=1: x has input dtype; XIN=0: x is internal fp32.
template <int K, int XIN>
__device__ __forceinline__ double wave_dot(const void* __restrict__ W,
                                           const void* __restrict__ x,
                                           int row, int lane, int bf) {
    double acc = 0.0;
    if (bf) {
        const ushort8v* Wr = (const ushort8v*)((const unsigned short*)W + (size_t)row * K);
        constexpr int NC = K / 512;               // 16B-vectors per lane
        if (XIN) {
            const ushort8v* xv = (const ushort8v*)x;
            #pragma unroll 8
            for (int c = 0; c < NC; ++c) {
                const int i = c * 64 + lane;
                ushort8v w = Wr[i], xx = xv[i];
                #pragma unroll
                for (int j = 0; j < 8; ++j)
                    acc += (double)bf2f(w[j]) * (double)bf2f(xx[j]);
            }
        } else {
            const float4* xv = (const float4*)x;
            #pragma unroll 8
            for (int c = 0; c < NC; ++c) {
                const int i = c * 64 + lane;
                ushort8v w = Wr[i];
                float4 x0 = xv[2 * i], x1 = xv[2 * i + 1];
                acc += (double)bf2f(w[0]) * (double)x0.x;
                acc += (double)bf2f(w[1]) * (double)x0.y;
                acc += (double)bf2f(w[2]) * (double)x0.z;
                acc += (double)bf2f(w[3]) * (double)x0.w;
                acc += (double)bf2f(w[4]) * (double)x1.x;
                acc += (double)bf2f(w[5]) * (double)x1.y;
                acc += (double)bf2f(w[6]) * (double)x1.z;
                acc += (double)bf2f(w[7]) * (double)x1.w;
            }
        }
    } else {
        const float4* Wr = (const float4*)((const float*)W + (size_t)row * K);
        const float4* xv = (const float4*)x;      // fp32 either way when !bf
        constexpr int NC = K / 256;
        #pragma unroll 8
        for (int c = 0; c < NC; ++c) {
            const int i = c * 64 + lane;
            float4 w = Wr[i], xx = xv[i];
            acc += (double)w.x * (double)xx.x;
            acc += (double)w.y * (double)xx.y;
            acc += (double)w.z * (double)xx.z;
            acc += (double)w.w * (double)xx.w;
        }
    }
    return wred(acc);
}

// Single cooperative kernel: 3 matvec phases separated by grid.sync(), then
// the Euler sim + loss. Removes 3 kernel-launch overheads and makes the whole
// pipeline one profilable dispatch.
__global__ __launch_bounds__(256, 4) void fused_kernel(
        const void* __restrict__ v_input, const void* __restrict__ target,
        const void* __restrict__ W1, const void* __restrict__ W2,
        const void* __restrict__ Wfb,
        const void* __restrict__ gain1, const void* __restrict__ gain2,
        float* __restrict__ h1c, float* __restrict__ io, float* __restrict__ hid,
        float* __restrict__ loss_out, float* __restrict__ vout,
        float* __restrict__ uout) {
    cg::grid_group grid = cg::this_grid();
    const int lane = threadIdx.x & 63;
    const int wave = threadIdx.x >> 6;
    const int gwid = blockIdx.x * 4 + wave;
    const int gwaves = gridDim.x * 4;
    const int bf = detect_bf(W1);

    // P1: h1c = compress(W1 @ v_input, gain1)
    for (int row = gwid; row < HSZ; row += gwaves) {
        double d = wave_dot<ISZ, 1>(W1, v_input, row, lane, bf);
        if (lane == 0) {
            const float g = bf ? bf2f(*(const unsigned short*)gain1)
                               : *(const float*)gain1;
            h1c[row] = (float)compress_d(d, (double)g);
        }
    }
    grid.sync();

    // P2: io = compress(W2 @ h1c, gain2)
    for (int row = gwid; row < OSZ; row += gwaves) {
        double d = wave_dot<HSZ, 0>(W2, h1c, row, lane, bf);
        if (lane == 0) {
            const float g = bf ? bf2f(*(const unsigned short*)gain2)
                               : *(const float*)gain2;
            io[row] = (float)compress_d(d, (double)g);
        }
    }
    grid.sync();

    // P3: hid = h1c - Wfb @ io
    for (int row = gwid; row < HSZ; row += gwaves) {
        double d = wave_dot<OSZ, 0>(Wfb, io, row, lane, bf);
        if (lane == 0) hid[row] = h1c[row] - (float)d;
    }
    grid.sync();

    // P4a: loss (one block), P4b: sim (grid-stride over neurons)
    if (blockIdx.x == gridDim.x - 1) {
        __shared__ double red[4];
        double acc = 0.0;
        for (int i = threadIdx.x; i < OSZ; i += 256) {
            const float tv = bf ? bf2f(((const unsigned short*)target)[i])
                                : ((const float*)target)[i];
            const double dd = (double)io[i] - (double)tv;
            acc += dd * dd;
        }
        acc = wred(acc);
        if ((threadIdx.x & 63) == 0) red[threadIdx.x >> 6] = acc;
        __syncthreads();
        if (threadIdx.x == 0)
            loss_out[0] = (float)((red[0] + red[1] + red[2] + red[3]) / (double)OSZ);
    }
    const int tid = blockIdx.x * 256 + threadIdx.x;
    for (int n = tid; n < NTOT; n += gridDim.x * 256) {
        const float ti = (n < HSZ) ? hid[n] : io[n - HSZ];
        float v = -65.0f;
        float u = -13.0f;               // 0.2f * -65.0f exactly
        vout[n] = v;
        uout[n] = u;
        for (int s = 1; s < STEPS; ++s) {
            // v_prev + DT*(((((0.04*v^2) + 5.0*v) + 0.14) - u) + ti)
            float dv = 0.04f * (v * v);
            dv = dv + 5.0f * v;
            dv = dv + 0.14f;
            dv = dv - u;
            dv = dv + ti;
            float vn = v + 1.0f * dv;
            // u_prev + (DT*A)*(B*v_prev - u_prev)
            float du = 0.2f * v - u;
            float un = u + 0.02f * du;
            bool sp = (vn >= 30.0f);
            v = sp ? -65.0f : vn;
            u = sp ? (un + 8.0f) : un;
            vout[(size_t)s * NTOT + n] = v;
            uout[(size_t)s * NTOT + n] = u;
        }
    }
}

// ---------------- fallback path (round-1 kernels, used if coop launch fails) --

template <int K, int XIN, int DOCOMP>
__global__ __launch_bounds__(256) void mv_kernel(
        const void* __restrict__ W, const void* __restrict__ x,
        const void* __restrict__ gain, const float* __restrict__ base,
        float* __restrict__ y, const void* __restrict__ Wdet) {
    const int bf = detect_bf(Wdet);
    const int row = blockIdx.x;
    const int t = threadIdx.x;
    double acc = 0.0;
    if (bf) {
        const ushort8v* Wr = (const ushort8v*)((const unsigned short*)W + (size_t)row * K);
        if (XIN) {
            const ushort8v* xv = (const ushort8v*)x;
            #pragma unroll
            for (int c = 0; c < K / 2048; ++c) {
                const int i = c * 256 + t;
                ushort8v w = Wr[i], xx = xv[i];
                #pragma unroll
                for (int j = 0; j < 8; ++j)
                    acc += (double)bf2f(w[j]) * (double)bf2f(xx[j]);
            }
        } else {
            const float4* xv = (const float4*)x;
            #pragma unroll
            for (int c = 0; c < K / 2048; ++c) {
                const int i = c * 256 + t;
                ushort8v w = Wr[i];
                float4 x0 = xv[2 * i], x1 = xv[2 * i + 1];
                acc += (double)bf2f(w[0]) * (double)x0.x;
                acc += (double)bf2f(w[1]) * (double)x0.y;
                acc += (double)bf2f(w[2]) * (double)x0.z;
                acc += (double)bf2f(w[3]) * (double)x0.w;
                acc += (double)bf2f(w[4]) * (double)x1.x;
                acc += (double)bf2f(w[5]) * (double)x1.y;
                acc += (double)bf2f(w[6]) * (double)x1.z;
                acc += (double)bf2f(w[7]) * (double)x1.w;
            }
        }
    } else {
        const float4* Wr = (const float4*)((const float*)W + (size_t)row * K);
        const float4* xv = (const float4*)x;
        #pragma unroll
        for (int c = 0; c < K / 1024; ++c) {
            const int i = c * 256 + t;
            float4 w = Wr[i], xx = xv[i];
            acc += (double)w.x * (double)xx.x;
            acc += (double)w.y * (double)xx.y;
            acc += (double)w.z * (double)xx.z;
            acc += (double)w.w * (double)xx.w;
        }
    }
    acc = wred(acc);
    __shared__ double red[4];
    if ((t & 63) == 0) red[t >> 6] = acc;
    __syncthreads();
    if (t == 0) {
        const double s = red[0] + red[1] + red[2] + red[3];
        if (DOCOMP) {
            const float g = bf ? bf2f(*(const unsigned short*)gain) : *(const float*)gain;
            y[row] = (float)compress_d(s, (double)g);
        } else {
            y[row] = base[row] - (float)s;
        }
    }
}

__global__ __launch_bounds__(256) void sim_loss_kernel(
        const float* __restrict__ hid, const float* __restrict__ io,
        const void* __restrict__ tgt, float* __restrict__ loss_out,
        float* __restrict__ vout, float* __restrict__ uout,
        const void* __restrict__ Wdet) {
    if (blockIdx.x == NTOT / 256) {
        const int bf = detect_bf(Wdet);
        __shared__ double red[4];
        double acc = 0.0;
        for (int i = threadIdx.x; i < OSZ; i += 256) {
            const float tv = bf ? bf2f(((const unsigned short*)tgt)[i])
                                : ((const float*)tgt)[i];
            const double d = (double)io[i] - (double)tv;
            acc += d * d;
        }
        acc = wred(acc);
        if ((threadIdx.x & 63) == 0) red[threadIdx.x >> 6] = acc;
        __syncthreads();
        if (threadIdx.x == 0)
            loss_out[0] = (float)((red[0] + red[1] + red[2] + red[3]) / (double)OSZ);
        return;
    }
    const int n = blockIdx.x * 256 + threadIdx.x;
    const float ti = (n < HSZ) ? hid[n] : io[n - HSZ];
    float v = -65.0f;
    float u = -13.0f;
    vout[n] = v;
    uout[n] = u;
    for (int s = 1; s < STEPS; ++s) {
        float dv = 0.04f * (v * v);
        dv = dv + 5.0f * v;
        dv = dv + 0.14f;
        dv = dv - u;
        dv = dv + ti;
        float vn = v + 1.0f * dv;
        float du = 0.2f * v - u;
        float un = u + 0.02f * du;
        bool sp = (vn >= 30.0f);
        v = sp ? -65.0f : vn;
        u = sp ? (un + 8.0f) : un;
        vout[(size_t)s * NTOT + n] = v;
        uout[(size_t)s * NTOT + n] = u;
    }
}

extern "C" void kernel_launch(void* const* d_in, const int* in_sizes, int n_in,
                              void* d_out, int out_size, void* d_ws, size_t ws_size,
                              hipStream_t stream) {
    const void* v_input = d_in[0];
    const void* target  = d_in[1];
    const void* W1      = d_in[2];
    const void* W2      = d_in[3];
    const void* Wfb     = d_in[4];
    const void* gain1   = d_in[5];
    const void* gain2   = d_in[6];

    float* out  = (float*)d_out;
    float* vout = out + 1;
    float* uout = out + 1 + (size_t)STEPS * NTOT;

    float* h1c = (float*)d_ws;    // [HSZ]
    float* io  = h1c + HSZ;       // [OSZ]
    float* hid = io + OSZ;        // [HSZ]

    // One-time co-residency sizing for the cooperative launch.
    static int coop_blocks = -2;  // -2 = not yet queried, -1 = disabled
    if (coop_blocks == -2) {
        int per_cu = 0, num_cu = 256, dev = 0;
        hipGetDevice(&dev);
        hipDeviceProp_t prop;
        if (hipGetDeviceProperties(&prop, dev) == hipSuccess && prop.multiProcessorCount > 0)
            num_cu = prop.multiProcessorCount;
        hipError_t e = hipOccupancyMaxActiveBlocksPerMultiprocessor(&per_cu, fused_kernel, 256, 0);
        if (e != hipSuccess || per_cu <= 0) {
            coop_blocks = -1;
        } else {
            long b = (long)per_cu * num_cu;
            if (b > 2048) b = 2048;
            coop_blocks = (int)b;
        }
    }

    if (coop_blocks > 0) {
        void* args[] = {
            (void*)&v_input, (void*)&target, (void*)&W1, (void*)&W2, (void*)&Wfb,
            (void*)&gain1, (void*)&gain2,
            (void*)&h1c, (void*)&io, (void*)&hid,
            (void*)&out, (void*)&vout, (void*)&uout,
        };
        hipError_t e = hipLaunchCooperativeKernel(fused_kernel, dim3(coop_blocks),
                                                  dim3(256), args, 0, stream);
        if (e == hipSuccess) return;
        coop_blocks = -1;   // launch rejected -> permanently fall back
    }

    // Fallback: 4-launch pipeline (round-1 behavior).
    mv_kernel<ISZ, 1, 1><<<HSZ, 256, 0, stream>>>(W1, v_input, gain1, nullptr, h1c, W1);
    mv_kernel<HSZ, 0, 1><<<OSZ, 256, 0, stream>>>(W2, h1c, gain2, nullptr, io, W1);
    mv_kernel<OSZ, 0, 0><<<HSZ, 256, 0, stream>>>(Wfb, io, nullptr, h1c, hid, W1);
    sim_loss_kernel<<<NTOT / 256 + 1, 256, 0, stream>>>(hid, io, target, out, vout, uout, W1);
}

// Round 3
// 578.725 us; speedup vs baseline: 1.1264x; 1.1264x over previous
//
#include <hip/hip_runtime.h>
#include <hip/hip_cooperative_groups.h>
#include <math.h>

namespace cg = cooperative_groups;

#define HSZ 8192
#define ISZ 4096
#define OSZ 4096
#define NTOT (HSZ + OSZ)
#define STEPS 100

typedef unsigned short ushort8v __attribute__((ext_vector_type(8)));

__device__ __forceinline__ float bf2f(unsigned short h) {
    union { unsigned u; float f; } c; c.u = ((unsigned)h) << 16; return c.f;
}

__device__ __forceinline__ double compress_d(double x, double gain) {
    // sign(x) * log1p(gain*|x| + 1e-6), sign(0)==0
    double s = (x > 0.0) ? 1.0 : ((x < 0.0) ? -1.0 : 0.0);
    return s * log1p(gain * fabs(x) + 1e-6);
}

__device__ __forceinline__ double wred(double a) {
    #pragma unroll
    for (int o = 32; o > 0; o >>= 1) a += __shfl_down(a, o, 64);
    return a;
}

// bf16-vs-fp32 detection, uniform per wave. W1 ~ U(0,0.05): true bf16 -> all
// |values| <= 0.05; fp32 bits read as ushorts -> random exponents, some
// |bf16(bits)| > 0.0625 (0x3D80) almost surely.
__device__ __forceinline__ int detect_bf(const void* W1) {
    const unsigned short* p = (const unsigned short*)W1;
    const int lane = threadIdx.x & 63;
    const unsigned short a0 = (unsigned short)(p[lane] & 0x7FFF);
    const unsigned short a1 = (unsigned short)(p[64 + lane] & 0x7FFF);
    unsigned long long bad = __ballot((a0 > 0x3D80) || (a1 > 0x3D80));
    return bad == 0ull;
}

// Exact f64 dot of W[row,:] with x, one wave (64 lanes), shfl-only reduction.
// EXPLICIT REGISTER STAGING: all loads of a group are issued into named
// registers BEFORE the f64 accumulate chain touches any of them. This is the
// MLP fix for round-2's 345 GB/s (VGPR=40 showed the compiler kept only one
// load in flight). All array indices are compile-time (full unroll) so the
// arrays live in VGPRs, not scratch.
template <int K, int XIN>
__device__ __forceinline__ double wave_dot(const void* __restrict__ W,
                                           const void* __restrict__ x,
                                           int row, int lane, int bf) {
    double acc = 0.0;
    if (bf) {
        const ushort8v* Wr = (const ushort8v*)((const unsigned short*)W + (size_t)row * K);
        constexpr int NC = K / 512;              // 16B W-chunks per lane
        constexpr int H  = (NC > 8) ? 8 : NC;    // staging group size
        if (XIN) {
            const ushort8v* xv = (const ushort8v*)x;
            #pragma unroll
            for (int base = 0; base < NC; base += H) {
                ushort8v w[H], xs[H];
                #pragma unroll
                for (int c = 0; c < H; ++c) w[c] = Wr[(base + c) * 64 + lane];
                #pragma unroll
                for (int c = 0; c < H; ++c) xs[c] = xv[(base + c) * 64 + lane];
                #pragma unroll
                for (int c = 0; c < H; ++c) {
                    #pragma unroll
                    for (int j = 0; j < 8; ++j)
                        acc += (double)bf2f(w[c][j]) * (double)bf2f(xs[c][j]);
                }
            }
        } else {
            const float4* xv = (const float4*)x;
            #pragma unroll
            for (int base = 0; base < NC; base += H) {
                ushort8v w[H];
                float4 xs[2 * H];
                #pragma unroll
                for (int c = 0; c < H; ++c) w[c] = Wr[(base + c) * 64 + lane];
                #pragma unroll
                for (int c = 0; c < H; ++c) {
                    const int i = (base + c) * 64 + lane;
                    xs[2 * c]     = xv[2 * i];
                    xs[2 * c + 1] = xv[2 * i + 1];
                }
                #pragma unroll
                for (int c = 0; c < H; ++c) {
                    acc += (double)bf2f(w[c][0]) * (double)xs[2 * c].x;
                    acc += (double)bf2f(w[c][1]) * (double)xs[2 * c].y;
                    acc += (double)bf2f(w[c][2]) * (double)xs[2 * c].z;
                    acc += (double)bf2f(w[c][3]) * (double)xs[2 * c].w;
                    acc += (double)bf2f(w[c][4]) * (double)xs[2 * c + 1].x;
                    acc += (double)bf2f(w[c][5]) * (double)xs[2 * c + 1].y;
                    acc += (double)bf2f(w[c][6]) * (double)xs[2 * c + 1].z;
                    acc += (double)bf2f(w[c][7]) * (double)xs[2 * c + 1].w;
                }
            }
        }
    } else {
        const float4* Wr = (const float4*)((const float*)W + (size_t)row * K);
        const float4* xv = (const float4*)x;     // fp32 either way when !bf
        constexpr int NC = K / 256;              // 16B W-chunks per lane
        constexpr int H  = (NC > 8) ? 8 : NC;
        #pragma unroll
        for (int base = 0; base < NC; base += H) {
            float4 w[H], xs[H];
            #pragma unroll
            for (int c = 0; c < H; ++c) w[c] = Wr[(base + c) * 64 + lane];
            #pragma unroll
            for (int c = 0; c < H; ++c) xs[c] = xv[(base + c) * 64 + lane];
            #pragma unroll
            for (int c = 0; c < H; ++c) {
                acc += (double)w[c].x * (double)xs[c].x;
                acc += (double)w[c].y * (double)xs[c].y;
                acc += (double)w[c].z * (double)xs[c].z;
                acc += (double)w[c].w * (double)xs[c].w;
            }
        }
    }
    return wred(acc);
}

// Single cooperative kernel: 3 matvec phases separated by grid.sync(), then
// Euler sim + loss. Sim is mapped one 64-neuron chunk per BLOCK so it spreads
// across ~192 CUs instead of 48.
__global__ __launch_bounds__(256, 4) void fused_kernel(
        const void* __restrict__ v_input, const void* __restrict__ target,
        const void* __restrict__ W1, const void* __restrict__ W2,
        const void* __restrict__ Wfb,
        const void* __restrict__ gain1, const void* __restrict__ gain2,
        float* __restrict__ h1c, float* __restrict__ io, float* __restrict__ hid,
        float* __restrict__ loss_out, float* __restrict__ vout,
        float* __restrict__ uout) {
    cg::grid_group grid = cg::this_grid();
    const int lane = threadIdx.x & 63;
    const int wave = threadIdx.x >> 6;
    const int gwid = blockIdx.x * 4 + wave;
    const int gwaves = gridDim.x * 4;
    const int bf = detect_bf(W1);

    // P1: h1c = compress(W1 @ v_input, gain1)
    for (int row = gwid; row < HSZ; row += gwaves) {
        double d = wave_dot<ISZ, 1>(W1, v_input, row, lane, bf);
        if (lane == 0) {
            const float g = bf ? bf2f(*(const unsigned short*)gain1)
                               : *(const float*)gain1;
            h1c[row] = (float)compress_d(d, (double)g);
        }
    }
    grid.sync();

    // P2: io = compress(W2 @ h1c, gain2)
    for (int row = gwid; row < OSZ; row += gwaves) {
        double d = wave_dot<HSZ, 0>(W2, h1c, row, lane, bf);
        if (lane == 0) {
            const float g = bf ? bf2f(*(const unsigned short*)gain2)
                               : *(const float*)gain2;
            io[row] = (float)compress_d(d, (double)g);
        }
    }
    grid.sync();

    // P3: hid = h1c - Wfb @ io
    for (int row = gwid; row < HSZ; row += gwaves) {
        double d = wave_dot<OSZ, 0>(Wfb, io, row, lane, bf);
        if (lane == 0) hid[row] = h1c[row] - (float)d;
    }
    grid.sync();

    // P4a: loss (last block)
    if (blockIdx.x == gridDim.x - 1) {
        __shared__ double red[4];
        double acc = 0.0;
        for (int i = threadIdx.x; i < OSZ; i += 256) {
            const float tv = bf ? bf2f(((const unsigned short*)target)[i])
                                : ((const float*)target)[i];
            const double dd = (double)io[i] - (double)tv;
            acc += dd * dd;
        }
        acc = wred(acc);
        if ((threadIdx.x & 63) == 0) red[threadIdx.x >> 6] = acc;
        __syncthreads();
        if (threadIdx.x == 0)
            loss_out[0] = (float)((red[0] + red[1] + red[2] + red[3]) / (double)OSZ);
    }

    // P4b: sim — one 64-neuron chunk per block (wave 0), block-stride.
    constexpr int NCHUNK = NTOT / 64;   // 192
    if (wave == 0) {
        for (int c = blockIdx.x; c < NCHUNK; c += gridDim.x) {
            const int n = c * 64 + lane;
            const float ti = (n < HSZ) ? hid[n] : io[n - HSZ];
            float v = -65.0f;
            float u = -13.0f;           // 0.2f * -65.0f exactly
            vout[n] = v;
            uout[n] = u;
            for (int s = 1; s < STEPS; ++s) {
                // v_prev + DT*(((((0.04*v^2) + 5.0*v) + 0.14) - u) + ti)
                float dv = 0.04f * (v * v);
                dv = dv + 5.0f * v;
                dv = dv + 0.14f;
                dv = dv - u;
                dv = dv + ti;
                float vn = v + 1.0f * dv;
                // u_prev + (DT*A)*(B*v_prev - u_prev)
                float du = 0.2f * v - u;
                float un = u + 0.02f * du;
                bool sp = (vn >= 30.0f);
                v = sp ? -65.0f : vn;
                u = sp ? (un + 8.0f) : un;
                vout[(size_t)s * NTOT + n] = v;
                uout[(size_t)s * NTOT + n] = u;
            }
        }
    }
}

// ---------------- fallback path (round-1 kernels, used if coop launch fails) --

template <int K, int XIN, int DOCOMP>
__global__ __launch_bounds__(256) void mv_kernel(
        const void* __restrict__ W, const void* __restrict__ x,
        const void* __restrict__ gain, const float* __restrict__ base,
        float* __restrict__ y, const void* __restrict__ Wdet) {
    const int bf = detect_bf(Wdet);
    const int lane = threadIdx.x & 63;
    const int wave = threadIdx.x >> 6;
    const int row = blockIdx.x * 4 + wave;
    double acc = wave_dot<K, XIN>(W, x, row, lane, bf);
    if (lane == 0) {
        if (DOCOMP) {
            const float g = bf ? bf2f(*(const unsigned short*)gain) : *(const float*)gain;
            y[row] = (float)compress_d(acc, (double)g);
        } else {
            y[row] = base[row] - (float)acc;
        }
    }
}

__global__ __launch_bounds__(256) void sim_loss_kernel(
        const float* __restrict__ hid, const float* __restrict__ io,
        const void* __restrict__ tgt, float* __restrict__ loss_out,
        float* __restrict__ vout, float* __restrict__ uout,
        const void* __restrict__ Wdet) {
    if (blockIdx.x == NTOT / 256) {
        const int bf = detect_bf(Wdet);
        __shared__ double red[4];
        double acc = 0.0;
        for (int i = threadIdx.x; i < OSZ; i += 256) {
            const float tv = bf ? bf2f(((const unsigned short*)tgt)[i])
                                : ((const float*)tgt)[i];
            const double d = (double)io[i] - (double)tv;
            acc += d * d;
        }
        acc = wred(acc);
        if ((threadIdx.x & 63) == 0) red[threadIdx.x >> 6] = acc;
        __syncthreads();
        if (threadIdx.x == 0)
            loss_out[0] = (float)((red[0] + red[1] + red[2] + red[3]) / (double)OSZ);
        return;
    }
    const int n = blockIdx.x * 256 + threadIdx.x;
    const float ti = (n < HSZ) ? hid[n] : io[n - HSZ];
    float v = -65.0f;
    float u = -13.0f;
    vout[n] = v;
    uout[n] = u;
    for (int s = 1; s < STEPS; ++s) {
        float dv = 0.04f * (v * v);
        dv = dv + 5.0f * v;
        dv = dv + 0.14f;
        dv = dv - u;
        dv = dv + ti;
        float vn = v + 1.0f * dv;
        float du = 0.2f * v - u;
        float un = u + 0.02f * du;
        bool sp = (vn >= 30.0f);
        v = sp ? -65.0f : vn;
        u = sp ? (un + 8.0f) : un;
        vout[(size_t)s * NTOT + n] = v;
        uout[(size_t)s * NTOT + n] = u;
    }
}

extern "C" void kernel_launch(void* const* d_in, const int* in_sizes, int n_in,
                              void* d_out, int out_size, void* d_ws, size_t ws_size,
                              hipStream_t stream) {
    const void* v_input = d_in[0];
    const void* target  = d_in[1];
    const void* W1      = d_in[2];
    const void* W2      = d_in[3];
    const void* Wfb     = d_in[4];
    const void* gain1   = d_in[5];
    const void* gain2   = d_in[6];

    float* out  = (float*)d_out;
    float* vout = out + 1;
    float* uout = out + 1 + (size_t)STEPS * NTOT;

    float* h1c = (float*)d_ws;    // [HSZ]
    float* io  = h1c + HSZ;       // [OSZ]
    float* hid = io + OSZ;        // [HSZ]

    // One-time co-residency sizing for the cooperative launch.
    static int coop_blocks = -2;  // -2 = not yet queried, -1 = disabled
    if (coop_blocks == -2) {
        int per_cu = 0, num_cu = 256, dev = 0;
        hipGetDevice(&dev);
        hipDeviceProp_t prop;
        if (hipGetDeviceProperties(&prop, dev) == hipSuccess && prop.multiProcessorCount > 0)
            num_cu = prop.multiProcessorCount;
        hipError_t e = hipOccupancyMaxActiveBlocksPerMultiprocessor(&per_cu, fused_kernel, 256, 0);
        if (e != hipSuccess || per_cu <= 0) {
            coop_blocks = -1;
        } else {
            long b = (long)per_cu * num_cu;
            if (b > 2048) b = 2048;
            coop_blocks = (int)b;
        }
    }

    if (coop_blocks > 0) {
        void* args[] = {
            (void*)&v_input, (void*)&target, (void*)&W1, (void*)&W2, (void*)&Wfb,
            (void*)&gain1, (void*)&gain2,
            (void*)&h1c, (void*)&io, (void*)&hid,
            (void*)&out, (void*)&vout, (void*)&uout,
        };
        hipError_t e = hipLaunchCooperativeKernel(fused_kernel, dim3(coop_blocks),
                                                  dim3(256), args, 0, stream);
        if (e == hipSuccess) return;
        coop_blocks = -1;   // launch rejected -> permanently fall back
    }

    // Fallback: 4-launch pipeline.
    mv_kernel<ISZ, 1, 1><<<HSZ / 4, 256, 0, stream>>>(W1, v_input, gain1, nullptr, h1c, W1);
    mv_kernel<HSZ, 0, 1><<<OSZ / 4, 256, 0, stream>>>(W2, h1c, gain2, nullptr, io, W1);
    mv_kernel<OSZ, 0, 0><<<HSZ / 4, 256, 0, stream>>>(Wfb, io, nullptr, h1c, hid, W1);
    sim_loss_kernel<<<NTOT / 256 + 1, 256, 0, stream>>>(hid, io, target, out, vout, uout, W1);
}